// Round 10
// baseline (587.326 us; speedup 1.0000x reference)
//
#include <hip/hip_runtime.h>
#include <cmath>

#define N_QUERY 16384
#define N_VOX   8192
#define BLOCK   512        // threads per block (8 waves)
#define VPT     16         // voxels per thread
#define NGROUP  4          // groups of 4 voxels per thread

typedef float f32x4 __attribute__((ext_vector_type(4)));

#if __has_builtin(__builtin_amdgcn_exp2f)
__device__ __forceinline__ float fast_exp2(float x) { return __builtin_amdgcn_exp2f(x); }
#else
__device__ __forceinline__ float fast_exp2(float x) { float r; asm("v_exp_f32 %0, %1" : "=v"(r) : "v"(x)); return r; }
#endif

#if __has_builtin(__builtin_amdgcn_sqrtf)
__device__ __forceinline__ float fast_sqrt(float x) { return __builtin_amdgcn_sqrtf(x); }
#else
__device__ __forceinline__ float fast_sqrt(float x) { float r; asm("v_sqrt_f32 %0, %1" : "=v"(r) : "v"(x)); return r; }
#endif

__device__ __forceinline__ float wave_reduce_sum(float v) {
    #pragma unroll
    for (int off = 32; off > 0; off >>= 1) v += __shfl_xor(v, off, 64);
    return v;
}

#define NEG_HALF_LOG2E (-0.7213475204444817f)   // -log2(e)/2  (sigma = 1)

// One query row per block; low VGPR -> >=3 blocks/CU resident (24 waves/CU).
// Independent blocks interleave compute/reduction/stores on each CU so the
// HBM write stream never idles (store duty-cycle theory).
__global__ __launch_bounds__(BLOCK, 6)
void voxel_interp_kernel(const float* __restrict__ qp,   // [N,3]
                         const float* __restrict__ vc,   // [M,3]
                         const float* __restrict__ vf,   // [M,4]
                         const float* __restrict__ vs,   // [M]
                         float* __restrict__ dens,       // [N]
                         float* __restrict__ cols,       // [N,3]
                         float* __restrict__ sizes,      // [N]
                         float* __restrict__ wout)       // [N,M]
{
    const int t = threadIdx.x;
    const int row = blockIdx.x;

    // uniform -> scalar loads
    const float qx = qp[row * 3 + 0];
    const float qy = qp[row * 3 + 1];
    const float qz = qp[row * 3 + 2];

    float w[VPT];                       // unnormalized weights (16 VGPRs)
    float asum = 0.f, af0 = 0.f, af1 = 0.f, af2 = 0.f, af3 = 0.f, asz = 0.f;

    #pragma unroll
    for (int g = 0; g < NGROUP; ++g) {
        const int v0 = g * (N_VOX / NGROUP) + t * 4;     // 16B-aligned
        const float4* cp = reinterpret_cast<const float4*>(vc + (size_t)v0 * 3);
        float4 c0 = cp[0], c1 = cp[1], c2 = cp[2];
        float cxs[4] = {c0.x, c0.w, c1.z, c2.y};
        float cys[4] = {c0.y, c1.x, c1.w, c2.z};
        float czs[4] = {c0.z, c1.y, c2.x, c2.w};
        const float4* fp = reinterpret_cast<const float4*>(vf + (size_t)v0 * 4);
        float4 fa[4] = {fp[0], fp[1], fp[2], fp[3]};
        float4 sz4 = *reinterpret_cast<const float4*>(vs + v0);
        float szs[4] = {sz4.x, sz4.y, sz4.z, sz4.w};

        #pragma unroll
        for (int i = 0; i < 4; ++i) {
            float dx = qx - cxs[i];
            float dy = qy - cys[i];
            float dz = qz - czs[i];
            float d2 = dx * dx + dy * dy + dz * dz;              // exact, >= 0
            float ww = fast_exp2(fast_sqrt(d2) * NEG_HALF_LOG2E); // exp(-d/2)
            w[g * 4 + i] = ww;
            asum += ww;
            af0 += ww * fa[i].x;
            af1 += ww * fa[i].y;
            af2 += ww * fa[i].z;
            af3 += ww * fa[i].w;
            asz += ww * szs[i];
        }
    }

    // ---- block reduction of 6 scalars ----
    float vals[6] = {asum, af0, af1, af2, af3, asz};

    __shared__ float red[BLOCK / 64][6];
    __shared__ float fin[6];
    const int wave = t >> 6;
    const int lane = t & 63;
    #pragma unroll
    for (int i = 0; i < 6; ++i) {
        float r = wave_reduce_sum(vals[i]);
        if (lane == 0) red[wave][i] = r;
    }
    __syncthreads();
    if (t < 6) {
        float s = 0.f;
        #pragma unroll
        for (int wv = 0; wv < BLOCK / 64; ++wv) s += red[wv][t];
        fin[t] = s;
    }
    __syncthreads();

    const float iv = 1.0f / (fin[0] + 1e-8f);

    // ---- streaming write of this row's normalized weights ----
    float* base = wout + (size_t)row * N_VOX;
    #pragma unroll
    for (int g = 0; g < NGROUP; ++g) {
        const int v0 = g * (N_VOX / NGROUP) + t * 4;
        f32x4 o;
        o.x = w[g * 4 + 0] * iv;
        o.y = w[g * 4 + 1] * iv;
        o.z = w[g * 4 + 2] * iv;
        o.w = w[g * 4 + 3] * iv;
        __builtin_nontemporal_store(o, reinterpret_cast<f32x4*>(base + v0));
    }

    // ---- tiny per-row outputs ----
    if (t == 0) {
        const float f0 = fin[1] * iv;
        const float f1 = fin[2] * iv;
        const float f2 = fin[3] * iv;
        const float f3 = fin[4] * iv;
        const float sz = fin[5] * iv;
        dens[row] = log1pf(expf(f0));                   // softplus
        cols[row * 3 + 0] = 1.0f / (1.0f + expf(-f1));  // sigmoid
        cols[row * 3 + 1] = 1.0f / (1.0f + expf(-f2));
        cols[row * 3 + 2] = 1.0f / (1.0f + expf(-f3));
        sizes[row] = sz;
    }
}

extern "C" void kernel_launch(void* const* d_in, const int* in_sizes, int n_in,
                              void* d_out, int out_size, void* d_ws, size_t ws_size,
                              hipStream_t stream) {
    const float* qp = (const float*)d_in[0];   // query_points [16384,3]
    const float* vc = (const float*)d_in[1];   // voxel_coords [8192,3]
    const float* vf = (const float*)d_in[2];   // voxel_features [8192,4]
    const float* vs = (const float*)d_in[3];   // voxel_sizes [8192]

    float* out   = (float*)d_out;
    float* dens  = out;                         // [16384]
    float* cols  = out + N_QUERY;               // [16384,3]
    float* sizes = out + N_QUERY * 4;           // [16384]
    float* wout  = out + N_QUERY * 5;           // [16384,8192]

    voxel_interp_kernel<<<dim3(N_QUERY), BLOCK, 0, stream>>>(
        qp, vc, vf, vs, dens, cols, sizes, wout);
}